// Round 4
// baseline (6007.756 us; speedup 1.0000x reference)
//
#include <hip/hip_runtime.h>
#include <hip/hip_bf16.h>

#define T_  512
#define FS_ 64
#define FC_ 32
#define H_  256
#define APAD 272

// ws layout (bf16 element offsets)
#define WS_REC0 0        // [32 ft][8 ks][64 lane][8]   even ft = Wg_h, odd = Wrec
#define WS_REC1 131072
#define WS_X1P  262144   // [32][8][64][8]              even ft = Win1, odd = Wg_x1
#define WS_X0S  393216   // [32][2][64][8]              even ft = Win0, odd = Wg_x0
#define WS_X0C  425984   // [32][1][64][8]
#define WS_MBOX 458752   // [32 tiles][2 parity][16*256] bf16 h0 mailbox
#define WS_FLAG_BYTE ((458752 + 262144) * 2)   // 128 ints: pub[64], ack[64]

typedef __attribute__((ext_vector_type(8))) short bfrag;
typedef __attribute__((ext_vector_type(4))) float ffrag;
typedef __attribute__((ext_vector_type(4))) float f32x4;

__device__ __forceinline__ ffrag mfma16(bfrag a, bfrag b, ffrag c) {
    return __builtin_amdgcn_mfma_f32_16x16x32_bf16(a, b, c, 0, 0, 0);
}
__device__ __forceinline__ float fast_tanh(float x) {
    float e = __builtin_amdgcn_exp2f(x * 2.8853901817f);   // exp(2x), inf-safe
    return 1.f - 2.f * __builtin_amdgcn_rcpf(e + 1.f);
}
__device__ __forceinline__ void bar_lds() {
    asm volatile("s_waitcnt lgkmcnt(0)\n\ts_barrier" ::: "memory");
}

// ---------------- prepack: fp32 weights -> bf16 MFMA B-fragments + flag reset ---
__global__ __launch_bounds__(256) void prepack_kernel(
    const float* __restrict__ Win0, const float* __restrict__ Wrec0, const float* __restrict__ Wg0,
    const float* __restrict__ Win1, const float* __restrict__ Wrec1, const float* __restrict__ Wg1,
    __hip_bfloat16* __restrict__ ws)
{
    int g = blockIdx.x * 256 + threadIdx.x;
    if (g < 128) ((int*)((char*)ws + WS_FLAG_BYTE))[g] = 0;   // pub/ack flags: reset every launch
    if (g >= 55296) return;
    int lane = g & 63;
    int frag = g >> 6;
    int lm = lane & 15, qq = lane >> 4;
    const float* src;
    int dstoff;
    if (frag < 256) {
        int f = frag, ft = f >> 3, ks = f & 7;
        int n = (ft >> 1) * 16 + lm, kk = ks * 32 + qq * 8;
        src = (ft & 1) ? (Wrec0 + n * 256 + kk) : (Wg0 + n * 352 + 96 + kk);
        dstoff = WS_REC0 + (f * 64 + lane) * 8;
    } else if (frag < 512) {
        int f = frag - 256, ft = f >> 3, ks = f & 7;
        int n = (ft >> 1) * 16 + lm, kk = ks * 32 + qq * 8;
        src = (ft & 1) ? (Wrec1 + n * 256 + kk) : (Wg1 + n * 512 + 256 + kk);
        dstoff = WS_REC1 + (f * 64 + lane) * 8;
    } else if (frag < 768) {
        int f = frag - 512, ft = f >> 3, ks = f & 7;
        int n = (ft >> 1) * 16 + lm, kk = ks * 32 + qq * 8;
        src = (ft & 1) ? (Wg1 + n * 512 + kk) : (Win1 + n * 256 + kk);
        dstoff = WS_X1P + (f * 64 + lane) * 8;
    } else if (frag < 832) {
        int f = frag - 768, ft = f >> 1, ks = f & 1;
        int n = (ft >> 1) * 16 + lm, kk = ks * 32 + qq * 8;
        src = (ft & 1) ? (Wg0 + n * 352 + kk) : (Win0 + n * 96 + kk);
        dstoff = WS_X0S + (f * 64 + lane) * 8;
    } else {
        int f = frag - 832, ft = f;
        int n = (ft >> 1) * 16 + lm, kk = qq * 8;
        src = (ft & 1) ? (Wg0 + n * 352 + 64 + kk) : (Win0 + n * 96 + 64 + kk);
        dstoff = WS_X0C + (f * 64 + lane) * 8;
    }
    __hip_bfloat16* d = ws + dstoff;
#pragma unroll
    for (int j = 0; j < 8; j++) d[j] = __float2bfloat16(src[j]);
}

// ---------------- main: 64 WGs = 32 layer-0 producers + 32 layer-1 consumers ----
// Transposed-MFMA variant: compute D^T = mfma(W, h) — A/B frag layouts are
// per-lane identical on gfx950, so the same prepacked fragments serve as the
// A-operand. Each lane then owns 4 CONSECUTIVE out-cols per block -> packed
// uint2/float4 LDS writes in the tail, float4 loadbase. Weights pinned in
// registers via asm clamps (R3's VGPR=128 showed they silently weren't).
// B reads the mailbox directly as MFMA B-operands (no LDS staging, no extra
// barrier); polls are per-wave; A loads seq per-wave (no xsb staging).
__global__ __launch_bounds__(512, 2) void lnn_main(
    const float* __restrict__ seq, const float* __restrict__ ctx,
    const float* __restrict__ tau0, const float* __restrict__ bg0,
    const float* __restrict__ lng0, const float* __restrict__ lnb0,
    const float* __restrict__ tau1, const float* __restrict__ bg1,
    const float* __restrict__ lng1, const float* __restrict__ lnb1,
    const float* __restrict__ cW1, const float* __restrict__ cb1,
    const float* __restrict__ cW2, const float* __restrict__ cb2,
    __hip_bfloat16* __restrict__ ws, float* __restrict__ out)
{
    __shared__ __align__(16) float hbuf[16][260];
    __shared__ __align__(16) float hn[16][260];
    __shared__ __align__(16) __hip_bfloat16 abf[2][16][APAD];
    __shared__ __align__(16) __hip_bfloat16 xsb[16][40];       // ctx staging (pre-loop only)
    __shared__ __align__(16) float lnw[256], lnb[256];

    const int tid  = threadIdx.x;
    const int wave = tid >> 6, lane = tid & 63;     // 8 waves
    const int qq   = lane >> 4, lm = lane & 15;
    const int bid  = blockIdx.x;
    const int tile = bid & 31, roleB = bid >> 5;
    const int brow = tile * 16;

    int* flags = (int*)((char*)ws + WS_FLAG_BYTE);
    int* pubf  = flags + tile * 2;          // [parity]
    int* ackf  = flags + 64 + tile * 2;     // [parity]
    __hip_bfloat16* mb0 = ws + WS_MBOX + tile * 2 * 4096;

    for (int e = tid; e < 16 * 260; e += 512) ((float*)hbuf)[e] = 0.f;
    for (int e = tid; e < 2 * 16 * APAD; e += 512)
        ((__hip_bfloat16*)abf)[e] = __float2bfloat16(0.f);
    if (tid < 256) {
        const float* lg = roleB ? lng1 : lng0;
        const float* lb = roleB ? lnb1 : lnb0;
        lnw[tid] = lg[tid]; lnb[tid] = lb[tid];
    }
    // per-(block, r) out-col params: n = wave*32 + b*16 + qq*4 + r
    float rtp_t[2][4], bgr_t[2][4];
#pragma unroll
    for (int b = 0; b < 2; b++)
#pragma unroll
        for (int r = 0; r < 4; r++) {
            int n = wave * 32 + b * 16 + qq * 4 + r;
            float tv = roleB ? tau1[n] : tau0[n];
            float sp = fmaxf(tv, 0.f) + logf(1.f + __expf(-fabsf(tv)));
            rtp_t[b][r] = 1.f / (sp + 1.f);
            bgr_t[b][r] = roleB ? bg1[n] : bg0[n];
        }

    // ---- pinned rec/gate weights: 2 col-blocks x 8 ks x (gate,rec) = 128 VGPR ----
    bfrag cg[2][8], cr[2][8];
    {
        const __hip_bfloat16* rp = ws + (roleB ? WS_REC1 : WS_REC0);
#pragma unroll
        for (int b = 0; b < 2; b++) {
            int ct = 2 * wave + b;
#pragma unroll
            for (int ks = 0; ks < 8; ks++) {
                cg[b][ks] = *(const bfrag*)(rp + ((16 * ct + ks) * 64 + lane) * 8);
                cr[b][ks] = *(const bfrag*)(rp + ((16 * ct + 8 + ks) * 64 + lane) * 8);
            }
        }
    }
    auto pinrec = [&]() {
#pragma unroll
        for (int b = 0; b < 2; b++)
#pragma unroll
            for (int ks = 0; ks < 8; ks++) {
                asm volatile("" : "+v"(cg[b][ks]));
                asm volatile("" : "+v"(cr[b][ks]));
            }
    };

    float xwin[2][4], xgate[2][4], hbase[2][4], hh[2][4], ksum[2][4];

    auto deriv = [&](const __hip_bfloat16 (*Ar)[APAD], __hip_bfloat16 (*Aw)[APAD], int d) {
        ffrag ag[2], ar[2];
#pragma unroll
        for (int b = 0; b < 2; b++) {
            ag[b] = (ffrag){0.f, 0.f, 0.f, 0.f};
            ar[b] = (ffrag){0.f, 0.f, 0.f, 0.f};
        }
#pragma unroll
        for (int ks = 0; ks < 8; ks++) {
            bfrag a = *(const bfrag*)&Ar[lm][ks * 32 + qq * 8];   // h as B-operand
            ag[0] = mfma16(cg[0][ks], a, ag[0]);
            ar[0] = mfma16(cr[0][ks], a, ar[0]);
            ag[1] = mfma16(cg[1][ks], a, ag[1]);
            ar[1] = mfma16(cr[1][ks], a, ar[1]);
        }
        float wsm = (d == 1 || d == 2) ? 2.f : 1.f;
        float an  = (d < 2) ? 0.5f : 1.f;
#pragma unroll
        for (int b = 0; b < 2; b++) {
            int n0b = wave * 32 + b * 16 + qq * 4;
            if (d < 3) {
                __align__(8) __hip_bfloat16 hb[4];
#pragma unroll
                for (int r = 0; r < 4; r++) {
                    float t  = fast_tanh(ag[b][r] + xgate[b][r]);
                    float t2 = t * t;
                    float g  = 0.5f + t * (0.25f + t2 * (-(1.f / 48.f) + t2 * (1.f / 480.f)));
                    float kd = xwin[b][r] - hh[b][r] * rtp_t[b][r] + g * ar[b][r];
                    ksum[b][r] += wsm * kd;
                    float hhn = hbase[b][r] + an * kd;
                    hh[b][r] = hhn;
                    hb[r] = __float2bfloat16(hhn);
                }
                *(uint2*)&Aw[lm][n0b] = *(uint2*)hb;       // packed 8B write
            } else {
                f32x4 o;
#pragma unroll
                for (int r = 0; r < 4; r++) {
                    float t  = fast_tanh(ag[b][r] + xgate[b][r]);
                    float t2 = t * t;
                    float g  = 0.5f + t * (0.25f + t2 * (-(1.f / 48.f) + t2 * (1.f / 480.f)));
                    float kd = xwin[b][r] - hh[b][r] * rtp_t[b][r] + g * ar[b][r];
                    ksum[b][r] += kd;
                    o[r] = hbase[b][r] + ksum[b][r] * (1.f / 6.f);
                }
                *(f32x4*)&hn[lm][n0b] = o;                 // packed 16B write
            }
        }
    };
    auto loadbase = [&]() {
#pragma unroll
        for (int b = 0; b < 2; b++) {
            int n0b = wave * 32 + b * 16 + qq * 4;
            f32x4 v = *(const f32x4*)&hbuf[lm][n0b];
#pragma unroll
            for (int r = 0; r < 4; r++) {
                hbase[b][r] = v[r]; hh[b][r] = v[r]; ksum[b][r] = 0.f;
            }
        }
    };
    auto lnorm = [&](__hip_bfloat16* mbslot, int t) {
        if (mbslot && t >= 2) {          // per-wave slot-free wait (B consumed t-2)
            int p = t & 1, guard = 1 << 27;
            while (__hip_atomic_load(&ackf[p], __ATOMIC_RELAXED,
                                     __HIP_MEMORY_SCOPE_AGENT) < t - 1 && --guard) {}
        }
#pragma unroll
        for (int i = 0; i < 2; i++) {                 // 8 waves x 2 rows = 16 rows
            int rr = wave + i * 8, c0 = lane * 4;
            f32x4 vv = *(const f32x4*)&hn[rr][c0];
            float v[4] = {vv[0], vv[1], vv[2], vv[3]};
            float s  = v[0] + v[1] + v[2] + v[3];
            float s2 = v[0]*v[0] + v[1]*v[1] + v[2]*v[2] + v[3]*v[3];
#pragma unroll
            for (int m = 1; m <= 32; m <<= 1) {
                s  += __shfl_xor(s, m, 64);
                s2 += __shfl_xor(s2, m, 64);
            }
            float mean = s * (1.f / 256.f);
            float var  = s2 * (1.f / 256.f) - mean * mean;
            float rs   = __builtin_amdgcn_rsqf(var + 1e-5f);
            f32x4 lw = *(const f32x4*)&lnw[c0];
            f32x4 lb = *(const f32x4*)&lnb[c0];
            float hv[4];
            __align__(8) __hip_bfloat16 hb[4];
#pragma unroll
            for (int j = 0; j < 4; j++) {
                hv[j] = fast_tanh((v[j] - mean) * rs * lw[j] + lb[j]);
                hb[j] = __float2bfloat16(hv[j]);
            }
            *(f32x4*)&hbuf[rr][c0] = (f32x4){hv[0], hv[1], hv[2], hv[3]};
            *(uint2*)&abf[0][rr][c0] = *(uint2*)hb;
            if (mbslot)
                __hip_atomic_store((unsigned long long*)&mbslot[rr * 256 + c0],
                                   *(unsigned long long*)hb,
                                   __ATOMIC_RELAXED, __HIP_MEMORY_SCOPE_AGENT);
        }
    };

    if (!roleB) {
        // =================== role A: layer 0 producer ===================
        for (int e = tid; e < 16 * FC_; e += 512) {
            int r = e >> 5, c = e & 31;
            xsb[r][c] = __float2bfloat16(ctx[(brow + r) * FC_ + c]);
        }
        __syncthreads();
        float xcw[2][4], xcg[2][4];
#pragma unroll
        for (int b = 0; b < 2; b++) {
            int ct = 2 * wave + b;
            bfrag a = *(const bfrag*)&xsb[lm][qq * 8];
            ffrag zw = {0.f, 0.f, 0.f, 0.f}, zg = {0.f, 0.f, 0.f, 0.f};
            bfrag bw  = *(const bfrag*)(ws + WS_X0C + ((2 * ct) * 64 + lane) * 8);
            bfrag bgf = *(const bfrag*)(ws + WS_X0C + ((2 * ct + 1) * 64 + lane) * 8);
            zw = mfma16(bw, a, zw);       // transposed: weights as A-operand
            zg = mfma16(bgf, a, zg);
#pragma unroll
            for (int r = 0; r < 4; r++) { xcw[b][r] = zw[r]; xcg[b][r] = zg[r]; }
        }
        __syncthreads();

        // seq B-operand prefetch (t=0): lane needs x[m=lm][k=qq*8(+32)+0..7]
        const float* sq0 = seq + ((size_t)(brow + lm) * T_) * FS_ + qq * 8;
        f32x4 sf0 = *(const f32x4*)(sq0);
        f32x4 sf1 = *(const f32x4*)(sq0 + 4);
        f32x4 sf2 = *(const f32x4*)(sq0 + 32);
        f32x4 sf3 = *(const f32x4*)(sq0 + 36);

#pragma unroll 1
        for (int t = 0; t < T_; t++) {
            int p = t & 1;
            pinrec();
            const __hip_bfloat16* x0s = ws + WS_X0S;
            asm volatile("" : "+s"(x0s));
            // build step-t seq frags from prefetched registers
            union { bfrag v; __hip_bfloat16 h[8]; } ua0, ua1;
#pragma unroll
            for (int j = 0; j < 4; j++) {
                ua0.h[j]     = __float2bfloat16(sf0[j]);
                ua0.h[j + 4] = __float2bfloat16(sf1[j]);
                ua1.h[j]     = __float2bfloat16(sf2[j]);
                ua1.h[j + 4] = __float2bfloat16(sf3[j]);
            }
            {   // issue t+1 prefetch now; lands during this step's derivs
                int tn = (t + 1 < T_) ? t + 1 : t;
                const float* sp = seq + ((size_t)(brow + lm) * T_ + tn) * FS_ + qq * 8;
                sf0 = *(const f32x4*)(sp);
                sf1 = *(const f32x4*)(sp + 4);
                sf2 = *(const f32x4*)(sp + 32);
                sf3 = *(const f32x4*)(sp + 36);
            }
            // x0 projection (transposed) + d0 — no staging barrier needed
#pragma unroll
            for (int b = 0; b < 2; b++) {
                int ct = 2 * wave + b;
                bfrag w0 = *(const bfrag*)(x0s + ((4 * ct + 0) * 64 + lane) * 8);
                bfrag w1 = *(const bfrag*)(x0s + ((4 * ct + 1) * 64 + lane) * 8);
                bfrag g0 = *(const bfrag*)(x0s + ((4 * ct + 2) * 64 + lane) * 8);
                bfrag g1 = *(const bfrag*)(x0s + ((4 * ct + 3) * 64 + lane) * 8);
                ffrag zw, zg;
#pragma unroll
                for (int r = 0; r < 4; r++) { zw[r] = xcw[b][r]; zg[r] = xcg[b][r] + bgr_t[b][r]; }
                zw = mfma16(w0, ua0.v, zw); zw = mfma16(w1, ua1.v, zw);
                zg = mfma16(g0, ua0.v, zg); zg = mfma16(g1, ua1.v, zg);
#pragma unroll
                for (int r = 0; r < 4; r++) { xwin[b][r] = zw[r]; xgate[b][r] = zg[r]; }
            }
            loadbase();
            deriv(abf[0], abf[1], 0);
            bar_lds(); deriv(abf[1], abf[0], 1);
            bar_lds(); deriv(abf[0], abf[1], 2);
            bar_lds(); deriv(abf[1], abf[0], 3);
            bar_lds();
            lnorm(mb0 + p * 4096, t);
            asm volatile("s_waitcnt vmcnt(0)" ::: "memory");   // drain sc1 stores
            __syncthreads();
            if (tid == 0)
                __hip_atomic_store(&pubf[p], t + 1, __ATOMIC_RELEASE,
                                   __HIP_MEMORY_SCOPE_AGENT);
        }
        return;
    }

    // =================== role B: layer 1 consumer + head ===================
#pragma unroll 1
    for (int t = 0; t < T_; t++) {
        int p = t & 1;
        pinrec();
        const __hip_bfloat16* xp = ws + WS_X1P;
        asm volatile("" : "+s"(xp));    // block LICM pinning of streamed x1p frags
        {   // per-wave wait for A's publish of step t (no WG barrier)
            int guard = 1 << 27;
            while (__hip_atomic_load(&pubf[p], __ATOMIC_RELAXED,
                                     __HIP_MEMORY_SCOPE_AGENT) < t + 1 && --guard) {}
        }
        // mailbox h0(t) read DIRECTLY as MFMA B-operands (shared by both blocks)
        bfrag am[8];
#pragma unroll
        for (int ks = 0; ks < 8; ks++) {
            const unsigned long long* q =
                (const unsigned long long*)(mb0 + p * 4096 + lm * 256 + ks * 32 + qq * 8);
            union { unsigned long long u[2]; bfrag v; } x;
            x.u[0] = __hip_atomic_load(q,     __ATOMIC_RELAXED, __HIP_MEMORY_SCOPE_AGENT);
            x.u[1] = __hip_atomic_load(q + 1, __ATOMIC_RELAXED, __HIP_MEMORY_SCOPE_AGENT);
            am[ks] = x.v;
        }
        {   // x1 projection (transposed): W streamed from L2 in halves
#pragma unroll
            for (int b = 0; b < 2; b++) {
                int ct = 2 * wave + b;
                ffrag zw, zg;
#pragma unroll
                for (int r = 0; r < 4; r++) { zw[r] = 0.f; zg[r] = bgr_t[b][r]; }
#pragma unroll
                for (int half = 0; half < 2; half++) {
                    bfrag wv[4], gv[4];
#pragma unroll
                    for (int j = 0; j < 4; j++) {
                        int ks = half * 4 + j;
                        wv[j] = *(const bfrag*)(xp + ((16 * ct + ks) * 64 + lane) * 8);
                        gv[j] = *(const bfrag*)(xp + ((16 * ct + 8 + ks) * 64 + lane) * 8);
                    }
#pragma unroll
                    for (int j = 0; j < 4; j++) {
                        int ks = half * 4 + j;
                        zw = mfma16(wv[j], am[ks], zw);
                        zg = mfma16(gv[j], am[ks], zg);
                    }
                }
#pragma unroll
                for (int r = 0; r < 4; r++) { xwin[b][r] = zw[r]; xgate[b][r] = zg[r]; }
            }
        }
        loadbase();
        deriv(abf[0], abf[1], 0);
        bar_lds();
        if (tid == 0)   // all waves' mailbox reads are consumed by this point
            __hip_atomic_store(&ackf[p], t + 1, __ATOMIC_RELEASE,
                               __HIP_MEMORY_SCOPE_AGENT);
        deriv(abf[1], abf[0], 1);
        bar_lds(); deriv(abf[0], abf[1], 2);
        bar_lds(); deriv(abf[1], abf[0], 3);
        bar_lds();
        lnorm(nullptr, t);
        __syncthreads();
    }

    // ---- head: hid = relu(h1 @ cW1^T + cb1); out = hid @ cW2^T + cb2 ----
#pragma unroll
    for (int i = 0; i < 2; i++) {
        int rr = wave + i * 8;
        float acc0 = cb1[lane], acc1 = cb1[lane + 64];
        const float* w0 = cW1 + (size_t)lane * H_;
        const float* w1 = cW1 + (size_t)(lane + 64) * H_;
        for (int k = 0; k < H_; k += 4) {
            f32x4 hv = *(const f32x4*)&hbuf[rr][k];
            acc0 += hv[0] * w0[k] + hv[1] * w0[k+1] + hv[2] * w0[k+2] + hv[3] * w0[k+3];
            acc1 += hv[0] * w1[k] + hv[1] * w1[k+1] + hv[2] * w1[k+2] + hv[3] * w1[k+3];
        }
        __syncthreads();
        hn[rr][lane]      = fmaxf(acc0, 0.f);
        hn[rr][lane + 64] = fmaxf(acc1, 0.f);
    }
    __syncthreads();
    if (tid < 16) {
        float acc = cb2[0];
        for (int k = 0; k < 128; k++) acc += hn[tid][k] * cW2[k];
        out[brow + tid] = acc;
    }
}

extern "C" void kernel_launch(void* const* d_in, const int* in_sizes, int n_in,
                              void* d_out, int out_size, void* d_ws, size_t ws_size,
                              hipStream_t stream) {
    const float* seq   = (const float*)d_in[0];
    const float* ctx   = (const float*)d_in[1];
    const float* tau0  = (const float*)d_in[2];
    const float* Win0  = (const float*)d_in[3];
    const float* Wrec0 = (const float*)d_in[4];
    const float* Wg0   = (const float*)d_in[5];
    const float* bg0   = (const float*)d_in[6];
    const float* lng0  = (const float*)d_in[7];
    const float* lnb0  = (const float*)d_in[8];
    const float* tau1  = (const float*)d_in[9];
    const float* Win1  = (const float*)d_in[10];
    const float* Wrec1 = (const float*)d_in[11];
    const float* Wg1   = (const float*)d_in[12];
    const float* bg1   = (const float*)d_in[13];
    const float* lng1  = (const float*)d_in[14];
    const float* lnb1  = (const float*)d_in[15];
    const float* cW1   = (const float*)d_in[16];
    const float* cb1   = (const float*)d_in[17];
    const float* cW2   = (const float*)d_in[18];
    const float* cb2   = (const float*)d_in[19];
    __hip_bfloat16* ws = (__hip_bfloat16*)d_ws;

    hipLaunchKernelGGL(prepack_kernel, dim3(216), dim3(256), 0, stream,
                       Win0, Wrec0, Wg0, Win1, Wrec1, Wg1, ws);
    hipLaunchKernelGGL(lnn_main, dim3(64), dim3(512), 0, stream,
                       seq, ctx, tau0, bg0, lng0, lnb0, tau1, bg1, lng1, lnb1,
                       cW1, cb1, cW2, cb2, ws, (float*)d_out);
}